// Round 9
// baseline (238.139 us; speedup 1.0000x reference)
//
#include <hip/hip_runtime.h>

#define LOG2E 1.4426950408889634f
#define QSCALE 0.08838834764831845f  // 128^-0.5

typedef float f32x4 __attribute__((ext_vector_type(4)));
typedef short s16x8 __attribute__((ext_vector_type(8)));
typedef unsigned short u16;

__device__ __forceinline__ u16 f2bf(float x){
  unsigned u = __builtin_bit_cast(unsigned, x);
  u += 0x7FFFu + ((u >> 16) & 1u);   // RNE
  return (u16)(u >> 16);
}
__device__ __forceinline__ float bf2f(u16 h){
  unsigned u = ((unsigned)h) << 16;
  return __builtin_bit_cast(float, u);
}

static __device__ __forceinline__ f32x4 mfma16(s16x8 a, s16x8 b, f32x4 c){
  return __builtin_amdgcn_mfma_f32_16x16x32_bf16(a, b, c, 0, 0, 0);
}

#define GL16(gp, lp) __builtin_amdgcn_global_load_lds( \
    (const __attribute__((address_space(1))) void*)(gp), \
    (__attribute__((address_space(3))) void*)(lp), 16, 0, 0)

// ---- kernel 1: fused prep (unchanged; passed rounds 4, 6, 8) ----
__global__ __launch_bounds__(256) void prep_kernel(
    const float* __restrict__ x,
    const float* __restrict__ Wq, const float* __restrict__ Wk,
    const float* __restrict__ Wv,
    u16* __restrict__ xh, u16* __restrict__ xl,
    u16* __restrict__ wth, u16* __restrict__ wtl){
  __shared__ float tile[64][65];
  int bidx = blockIdx.x;
  if (bidx < 4096){
    size_t i = ((size_t)bidx * 256 + threadIdx.x) * 8;
    float4 a = *(const float4*)(x + i);
    float4 b = *(const float4*)(x + i + 4);
    float v[8] = {a.x, a.y, a.z, a.w, b.x, b.y, b.z, b.w};
    s16x8 vh, vl;
#pragma unroll
    for (int j = 0; j < 8; ++j){
      u16 h = f2bf(v[j]);
      vh[j] = (short)h;
      vl[j] = (short)f2bf(v[j] - bf2f(h));
    }
    *(s16x8*)(xh + i) = vh;
    *(s16x8*)(xl + i) = vl;
  } else {
    int blk = bidx - 4096;           // 96 = 3 * 16 * 2
    int w = blk >> 5; int rem = blk & 31;
    int k0 = (rem >> 1) * 64, d0 = (rem & 1) * 64;
    const float* W = (w == 0) ? Wq : ((w == 1) ? Wk : Wv);
    int t = threadIdx.x;
#pragma unroll
    for (int i = 0; i < 16; ++i){
      int idx = t + i * 256;
      int kk = idx >> 6, dd = idx & 63;
      tile[kk][dd] = W[(size_t)(k0 + kk) * 128 + d0 + dd];
    }
    __syncthreads();
#pragma unroll
    for (int i = 0; i < 16; ++i){
      int idx = t + i * 256;
      int dd = idx >> 6, kk = idx & 63;
      float v = tile[kk][dd];
      u16 h = f2bf(v);
      u16 lo = f2bf(v - bf2f(h));
      size_t o = (size_t)(w * 128 + d0 + dd) * 1024 + k0 + kk;
      wth[o] = h; wtl[o] = lo;
    }
  }
}

// ---- kernel 2: QKV GEMM (unchanged from rounds 6/8; awaiting counters) ----
__global__ __launch_bounds__(256) void qkv_gemm_kernel(
    const u16* __restrict__ xh, const u16* __restrict__ xl,
    const u16* __restrict__ wth, const u16* __restrict__ wtl,
    u16* __restrict__ qh, u16* __restrict__ ql,
    u16* __restrict__ kh, u16* __restrict__ kl,
    u16* __restrict__ vth, u16* __restrict__ vtl){
  __shared__ u16 Ah[128 * 64], Al[128 * 64], Bh[48 * 64], Bl[48 * 64];
  int bid = blockIdx.x;              // 512
  int xcd = bid & 7, s = bid >> 3;   // s in [0,64)
  int mx = (xcd << 3) | (s >> 3);    // 0..63
  int ty = s & 7;                    // 0..7, fastest -> A L2 reuse
  int m0 = mx * 128;
  int n0 = ty * 48;
  int t = threadIdx.x;
  int lane = t & 63, wv = t >> 6;
  int c = lane & 15, g = lane >> 4;
  int wm = wv * 32;                  // wave-tile 32m x 48n
  f32x4 acc[2][3] = {};

  for (int kt = 0; kt < 16; ++kt){
    int k0 = kt * 64;
    __syncthreads();
#pragma unroll
    for (int i = 0; i < 4; ++i){     // A hi+lo
      int L0 = (wv * 4 + i) * 64;
      int L = L0 + lane;
      int row = L >> 3, ch = (L & 7) * 8;
      size_t go = (size_t)(m0 + row) * 1024 + k0 + ch;
      GL16(xh + go, &Ah[L0 * 8]);
      GL16(xl + go, &Al[L0 * 8]);
    }
#pragma unroll
    for (int i = 0; i < 3; ++i){     // B hi(6)+lo(6)
      int j = wv * 3 + i;
      int jj = (j < 6) ? j : j - 6;
      int L0 = jj * 64;
      int L = L0 + lane;
      int row = L >> 3, ch = (L & 7) * 8;
      size_t go = (size_t)(n0 + row) * 1024 + k0 + ch;
      if (j < 6) GL16(wth + go, &Bh[L0 * 8]);
      else       GL16(wtl + go, &Bl[L0 * 8]);
    }
    __syncthreads();
#pragma unroll
    for (int ks = 0; ks < 2; ++ks){
      s16x8 af_h[2], af_l[2], bf_h[3], bf_l[3];
#pragma unroll
      for (int mf = 0; mf < 2; ++mf){
        int off = (wm + mf * 16 + c) * 64 + ks * 32 + g * 8;
        af_h[mf] = *(const s16x8*)&Ah[off];
        af_l[mf] = *(const s16x8*)&Al[off];
      }
#pragma unroll
      for (int nf = 0; nf < 3; ++nf){
        int off = (nf * 16 + c) * 64 + ks * 32 + g * 8;
        bf_h[nf] = *(const s16x8*)&Bh[off];
        bf_l[nf] = *(const s16x8*)&Bl[off];
      }
#pragma unroll
      for (int mf = 0; mf < 2; ++mf)
#pragma unroll
        for (int nf = 0; nf < 3; ++nf){
          acc[mf][nf] = mfma16(af_h[mf], bf_h[nf], acc[mf][nf]);
          acc[mf][nf] = mfma16(af_h[mf], bf_l[nf], acc[mf][nf]);
          acc[mf][nf] = mfma16(af_l[mf], bf_h[nf], acc[mf][nf]);
        }
    }
  }

#pragma unroll
  for (int mf = 0; mf < 2; ++mf)
#pragma unroll
    for (int nf = 0; nf < 3; ++nf){
      int base_n = n0 + nf * 16;
      int m_base = m0 + wm + mf * 16 + g * 4;
      if (base_n < 256){
        float sc = (base_n < 128) ? QSCALE : 1.0f;
        u16* oh = (base_n < 128) ? qh : kh;
        u16* ol = (base_n < 128) ? ql : kl;
        int d = (base_n & 127) + c;
#pragma unroll
        for (int r = 0; r < 4; ++r){
          float v = acc[mf][nf][r] * sc;
          u16 h = f2bf(v);
          u16 lo = f2bf(v - bf2f(h));
          size_t o = (size_t)(m_base + r) * 128 + d;
          oh[o] = h; ol[o] = lo;
        }
      } else {                       // v, stored transposed [b][d][t]
        int d = base_n - 256 + c;
        int bb = m_base >> 11;
        int tt = m_base & 2047;
        ushort4 ovh, ovl;
#pragma unroll
        for (int r = 0; r < 4; ++r){
          float v = acc[mf][nf][r];
          u16 h = f2bf(v);
          u16 lo = f2bf(v - bf2f(h));
          ((u16*)&ovh)[r] = h;
          ((u16*)&ovl)[r] = lo;
        }
        size_t o = (size_t)bb * (128 * 2048) + (size_t)d * 2048 + tt;
        *(ushort4*)&vth[o] = ovh;
        *(ushort4*)&vtl[o] = ovl;
      }
    }
}

// ---- kernel 3: split-K flash attention partials, v3: d-split wave pairs ----
// Block = one chunk (b, qt, j: up to 4 k-tiles). The block's 2 waves run the
// IDENTICAL r6-validated inner body (VGPR 76, batch-8 loads) for QK^T and
// softmax (duplicated compute, ~3 us total), but each wave owns only d-half
// w*64..w*64+63 of V and O: per-wave loads 64->48 per tile, accO 32->16 VGPR,
// waves 2304->4608 (18/CU ideal vs 9). K loads duplicated within the block
// land in L1 (waves in lockstep). Partial record unchanged; wave 0 writes
// m/l, each wave writes its 64-col O slice.
__global__ __launch_bounds__(128, 3) void attn_partial_kernel(
    const u16* __restrict__ qh, const u16* __restrict__ ql,
    const u16* __restrict__ kh, const u16* __restrict__ kl,
    const u16* __restrict__ vth, const u16* __restrict__ vtl,
    float* __restrict__ partials){
  __shared__ u16 Ph[2][16 * 88], Pl[2][16 * 88];
  int t = threadIdx.x;
  int lane = t & 63, wv = t >> 6;    // wv = d-half owner
  int c = lane & 15, g = lane >> 4;
  int cid = blockIdx.x;              // [0, 2304), one chunk per block
  int b = cid / 576;
  int r2 = cid - b * 576;
  int a = 0;
#pragma unroll
  for (int aa = 1; aa < 8; ++aa) if (r2 >= 8 * aa * (aa + 1)) a = aa;
  int off = r2 - 8 * a * (a + 1);    // [0, 16*(a+1))
  int qt_l = off / (a + 1);
  int j = off - qt_l * (a + 1);
  int qt = a * 16 + qt_l;
  int q0 = qt * 16;
  int n = (qt >> 2) + 1;             // total k-tiles for this q-tile
  int kt_lo = j * 4;
  int kt_hi = min(kt_lo + 4, n);
  u16* ph = Ph[wv];
  u16* pl = Pl[wv];

  size_t qrow = ((size_t)b * 2048 + q0 + c) * 128;
  s16x8 qbh[4], qbl[4];
#pragma unroll
  for (int ks = 0; ks < 4; ++ks){
    qbh[ks] = *(const s16x8*)&qh[qrow + ks * 32 + g * 8];
    qbl[ks] = *(const s16x8*)&ql[qrow + ks * 32 + g * 8];
  }

  f32x4 accO[4] = {};                // O^T d-tiles wv*64 + {0,16,32,48}
  float m = -INFINITY, lsum = 0.f;

  for (int kt = kt_lo; kt < kt_hi; ++kt){
    // ---- S^T tile [64k x 16q]: batch 8 loads per ks for ILP (r6 shape) ----
    f32x4 s4[4] = {};
    size_t kbase = ((size_t)b * 2048 + kt * 64 + c) * 128;
#pragma unroll
    for (int ks = 0; ks < 4; ++ks){
      s16x8 ah[4], al[4];
#pragma unroll
      for (int kb = 0; kb < 4; ++kb){
        size_t krow = kbase + (size_t)kb * (16 * 128) + ks * 32 + g * 8;
        ah[kb] = *(const s16x8*)&kh[krow];
        al[kb] = *(const s16x8*)&kl[krow];
      }
#pragma unroll
      for (int kb = 0; kb < 4; ++kb){
        s4[kb] = mfma16(ah[kb], qbh[ks], s4[kb]);
        s4[kb] = mfma16(ah[kb], qbl[ks], s4[kb]);
        s4[kb] = mfma16(al[kb], qbh[ks], s4[kb]);
      }
    }
    if (kt == n - 1){                // causal mask, last tile only
#pragma unroll
      for (int kb = 0; kb < 4; ++kb)
#pragma unroll
        for (int r = 0; r < 4; ++r){
          int kg = kt * 64 + kb * 16 + g * 4 + r;
          if (kg > q0 + c) s4[kb][r] = -3.0e38f;
        }
    }
    // ---- online softmax (row = query = lane&15; 4 lanes per row) ----
    float pmax = s4[0][0];
#pragma unroll
    for (int kb = 0; kb < 4; ++kb)
#pragma unroll
      for (int r = 0; r < 4; ++r) pmax = fmaxf(pmax, s4[kb][r]);
    pmax = fmaxf(pmax, __shfl_xor(pmax, 16));
    pmax = fmaxf(pmax, __shfl_xor(pmax, 32));
    float mnew = fmaxf(m, pmax);
    float corr = exp2f((m - mnew) * LOG2E);
    float psum = 0.f;
#pragma unroll
    for (int kb = 0; kb < 4; ++kb){
      ushort4 wh_, wl_;
#pragma unroll
      for (int r = 0; r < 4; ++r){
        float p = exp2f((s4[kb][r] - mnew) * LOG2E);
        psum += p;
        u16 h = f2bf(p);
        ((u16*)&wh_)[r] = h;
        ((u16*)&wl_)[r] = f2bf(p - bf2f(h));
      }
      *(ushort4*)&ph[c * 88 + kb * 16 + g * 4] = wh_;
      *(ushort4*)&pl[c * 88 + kb * 16 + g * 4] = wl_;
    }
    psum += __shfl_xor(psum, 16);
    psum += __shfl_xor(psum, 32);
    lsum = lsum * corr + psum;
    m = mnew;
#pragma unroll
    for (int dl = 0; dl < 4; ++dl)
#pragma unroll
      for (int r = 0; r < 4; ++r) accO[dl][r] *= corr;

    // intra-wave LDS bounce: C-layout P -> B-fragment layout (wave-private)
    asm volatile("s_waitcnt lgkmcnt(0)" ::: "memory");
    s16x8 pbh[2], pbl[2];
#pragma unroll
    for (int ks2 = 0; ks2 < 2; ++ks2){
      pbh[ks2] = *(const s16x8*)&ph[c * 88 + ks2 * 32 + g * 8];
      pbl[ks2] = *(const s16x8*)&pl[c * 88 + ks2 * 32 + g * 8];
    }
    // ---- O^T += V^T . P^T over this wave's d-half (4 tiles, batch by 2) ----
    size_t vbase = ((size_t)b * 128 + wv * 64 + c) * 2048 + (size_t)kt * 64;
#pragma unroll
    for (int dh = 0; dh < 2; ++dh){
      s16x8 vh8[2][2], vl8[2][2];
#pragma unroll
      for (int i = 0; i < 2; ++i){
        int dl = dh * 2 + i;
        size_t vrow = vbase + (size_t)dl * (16 * 2048);
#pragma unroll
        for (int ks2 = 0; ks2 < 2; ++ks2){
          vh8[i][ks2] = *(const s16x8*)&vth[vrow + ks2 * 32 + g * 8];
          vl8[i][ks2] = *(const s16x8*)&vtl[vrow + ks2 * 32 + g * 8];
        }
      }
#pragma unroll
      for (int i = 0; i < 2; ++i){
        int dl = dh * 2 + i;
#pragma unroll
        for (int ks2 = 0; ks2 < 2; ++ks2){
          accO[dl] = mfma16(vh8[i][ks2], pbh[ks2], accO[dl]);
          accO[dl] = mfma16(vh8[i][ks2], pbl[ks2], accO[dl]);
          accO[dl] = mfma16(vl8[i][ks2], pbh[ks2], accO[dl]);
        }
      }
    }
  }

  // ---- write partial: [cid]{ m[16], l[16], O[16 q][128 d] } ----
  float* pb = partials + (size_t)cid * 2080;
  if (wv == 0 && g == 0){ pb[c] = m; pb[16 + c] = lsum; }
#pragma unroll
  for (int dl = 0; dl < 4; ++dl){
    float4 o4;
    o4.x = accO[dl][0]; o4.y = accO[dl][1];
    o4.z = accO[dl][2]; o4.w = accO[dl][3];
    *(float4*)&pb[32 + c * 128 + wv * 64 + dl * 16 + g * 4] = o4;
  }
}

// ---- kernel 4: merge partials per (b, qt) (unchanged) ----
__global__ __launch_bounds__(256) void attn_merge_kernel(
    const float* __restrict__ partials, float* __restrict__ out){
  int bid = blockIdx.x;              // 512
  int b = bid >> 7, qt = bid & 127;
  int a = qt >> 4, r = qt & 15;
  int nc = a + 1;
  int cid0 = b * 576 + 8 * a * (a + 1) + r * (a + 1);
  int t = threadIdx.x;
  int q = t >> 4, dgrp = t & 15;
  int d0 = dgrp * 8;

  float M = -INFINITY;
#pragma unroll 1
  for (int w = 0; w < nc; ++w)
    M = fmaxf(M, partials[(size_t)(cid0 + w) * 2080 + q]);
  float L = 0.f;
  float o[8] = {0,0,0,0,0,0,0,0};
#pragma unroll 1
  for (int w = 0; w < nc; ++w){
    const float* pb = partials + (size_t)(cid0 + w) * 2080;
    float sc = exp2f((pb[q] - M) * LOG2E);
    L += pb[16 + q] * sc;
    float4 x0 = *(const float4*)&pb[32 + q * 128 + d0];
    float4 x1 = *(const float4*)&pb[32 + q * 128 + d0 + 4];
    o[0] += sc * x0.x; o[1] += sc * x0.y; o[2] += sc * x0.z; o[3] += sc * x0.w;
    o[4] += sc * x1.x; o[5] += sc * x1.y; o[6] += sc * x1.z; o[7] += sc * x1.w;
  }
  float invL = 1.0f / L;
  size_t obase = ((size_t)b * 2048 + qt * 16 + q) * 128 + d0;
  float4 r0, r1;
  r0.x = o[0] * invL; r0.y = o[1] * invL; r0.z = o[2] * invL; r0.w = o[3] * invL;
  r1.x = o[4] * invL; r1.y = o[5] * invL; r1.z = o[6] * invL; r1.w = o[7] * invL;
  *(float4*)&out[obase] = r0;
  *(float4*)&out[obase + 4] = r1;
}

extern "C" void kernel_launch(void* const* d_in, const int* in_sizes, int n_in,
                              void* d_out, int out_size, void* d_ws, size_t ws_size,
                              hipStream_t stream){
  (void)in_sizes; (void)n_in; (void)out_size;
  const float* x  = (const float*)d_in[0];
  const float* Wq = (const float*)d_in[1];
  const float* Wk = (const float*)d_in[2];
  const float* Wv = (const float*)d_in[3];
  float* out = (float*)d_out;

  char* ws = (char*)d_ws;
  size_t off = 0;
  auto alloc = [&](size_t bytes) -> void* {
    void* p = ws + off;
    off += (bytes + 255) & ~(size_t)255;
    return p;
  };
  u16* xh  = (u16*)alloc((size_t)8192 * 1024 * 2);
  u16* xl  = (u16*)alloc((size_t)8192 * 1024 * 2);
  u16* wth = (u16*)alloc((size_t)384 * 1024 * 2);
  u16* wtl = (u16*)alloc((size_t)384 * 1024 * 2);
  u16* qh  = (u16*)alloc((size_t)8192 * 128 * 2);
  u16* ql  = (u16*)alloc((size_t)8192 * 128 * 2);
  u16* kh  = (u16*)alloc((size_t)8192 * 128 * 2);
  u16* kl  = (u16*)alloc((size_t)8192 * 128 * 2);
  u16* vth = (u16*)alloc((size_t)8192 * 128 * 2);
  u16* vtl = (u16*)alloc((size_t)8192 * 128 * 2);
  // Partials (2304 x 2080 f32 = 19.2 MB) reuse xh/xl (32 MB), dead after gemm.
  float* partials = (float*)xh;

  if (ws_size < off) return;  // never write past the workspace

  prep_kernel<<<4192, 256, 0, stream>>>(x, Wq, Wk, Wv, xh, xl, wth, wtl);
  qkv_gemm_kernel<<<512, 256, 0, stream>>>(xh, xl, wth, wtl,
                                           qh, ql, kh, kl, vth, vtl);
  attn_partial_kernel<<<2304, 128, 0, stream>>>(qh, ql, kh, kl, vth, vtl,
                                                partials);
  attn_merge_kernel<<<512, 256, 0, stream>>>(partials, out);
}

// Round 11
// 150.380 us; speedup vs baseline: 1.5836x; 1.5836x over previous
//
#include <hip/hip_runtime.h>

#define LOG2E 1.4426950408889634f
#define QSCALE 0.08838834764831845f  // 128^-0.5

typedef float f32x4 __attribute__((ext_vector_type(4)));
typedef short s16x8 __attribute__((ext_vector_type(8)));
typedef unsigned short u16;

__device__ __forceinline__ u16 f2bf(float x){
  unsigned u = __builtin_bit_cast(unsigned, x);
  u += 0x7FFFu + ((u >> 16) & 1u);   // RNE
  return (u16)(u >> 16);
}
__device__ __forceinline__ float bf2f(u16 h){
  unsigned u = ((unsigned)h) << 16;
  return __builtin_bit_cast(float, u);
}

static __device__ __forceinline__ f32x4 mfma16(s16x8 a, s16x8 b, f32x4 c){
  return __builtin_amdgcn_mfma_f32_16x16x32_bf16(a, b, c, 0, 0, 0);
}

#define GL16(gp, lp) __builtin_amdgcn_global_load_lds( \
    (const __attribute__((address_space(1))) void*)(gp), \
    (__attribute__((address_space(3))) void*)(lp), 16, 0, 0)

// ---- kernel 1: fused prep (unchanged; passed rounds 4, 6, 8, 9) ----
__global__ __launch_bounds__(256) void prep_kernel(
    const float* __restrict__ x,
    const float* __restrict__ Wq, const float* __restrict__ Wk,
    const float* __restrict__ Wv,
    u16* __restrict__ xh, u16* __restrict__ xl,
    u16* __restrict__ wth, u16* __restrict__ wtl){
  __shared__ float tile[64][65];
  int bidx = blockIdx.x;
  if (bidx < 4096){
    size_t i = ((size_t)bidx * 256 + threadIdx.x) * 8;
    float4 a = *(const float4*)(x + i);
    float4 b = *(const float4*)(x + i + 4);
    float v[8] = {a.x, a.y, a.z, a.w, b.x, b.y, b.z, b.w};
    s16x8 vh, vl;
#pragma unroll
    for (int j = 0; j < 8; ++j){
      u16 h = f2bf(v[j]);
      vh[j] = (short)h;
      vl[j] = (short)f2bf(v[j] - bf2f(h));
    }
    *(s16x8*)(xh + i) = vh;
    *(s16x8*)(xl + i) = vl;
  } else {
    int blk = bidx - 4096;           // 96 = 3 * 16 * 2
    int w = blk >> 5; int rem = blk & 31;
    int k0 = (rem >> 1) * 64, d0 = (rem & 1) * 64;
    const float* W = (w == 0) ? Wq : ((w == 1) ? Wk : Wv);
    int t = threadIdx.x;
#pragma unroll
    for (int i = 0; i < 16; ++i){
      int idx = t + i * 256;
      int kk = idx >> 6, dd = idx & 63;
      tile[kk][dd] = W[(size_t)(k0 + kk) * 128 + d0 + dd];
    }
    __syncthreads();
#pragma unroll
    for (int i = 0; i < 16; ++i){
      int idx = t + i * 256;
      int dd = idx >> 6, kk = idx & 63;
      float v = tile[kk][dd];
      u16 h = f2bf(v);
      u16 lo = f2bf(v - bf2f(h));
      size_t o = (size_t)(w * 128 + d0 + dd) * 1024 + k0 + kk;
      wth[o] = h; wtl[o] = lo;
    }
  }
}

// ---- kernel 2: QKV GEMM (unchanged from rounds 6/8/9; awaiting counters) ----
__global__ __launch_bounds__(256) void qkv_gemm_kernel(
    const u16* __restrict__ xh, const u16* __restrict__ xl,
    const u16* __restrict__ wth, const u16* __restrict__ wtl,
    u16* __restrict__ qh, u16* __restrict__ ql,
    u16* __restrict__ kh, u16* __restrict__ kl,
    u16* __restrict__ vth, u16* __restrict__ vtl){
  __shared__ u16 Ah[128 * 64], Al[128 * 64], Bh[48 * 64], Bl[48 * 64];
  int bid = blockIdx.x;              // 512
  int xcd = bid & 7, s = bid >> 3;   // s in [0,64)
  int mx = (xcd << 3) | (s >> 3);    // 0..63
  int ty = s & 7;                    // 0..7, fastest -> A L2 reuse
  int m0 = mx * 128;
  int n0 = ty * 48;
  int t = threadIdx.x;
  int lane = t & 63, wv = t >> 6;
  int c = lane & 15, g = lane >> 4;
  int wm = wv * 32;                  // wave-tile 32m x 48n
  f32x4 acc[2][3] = {};

  for (int kt = 0; kt < 16; ++kt){
    int k0 = kt * 64;
    __syncthreads();
#pragma unroll
    for (int i = 0; i < 4; ++i){     // A hi+lo
      int L0 = (wv * 4 + i) * 64;
      int L = L0 + lane;
      int row = L >> 3, ch = (L & 7) * 8;
      size_t go = (size_t)(m0 + row) * 1024 + k0 + ch;
      GL16(xh + go, &Ah[L0 * 8]);
      GL16(xl + go, &Al[L0 * 8]);
    }
#pragma unroll
    for (int i = 0; i < 3; ++i){     // B hi(6)+lo(6)
      int j = wv * 3 + i;
      int jj = (j < 6) ? j : j - 6;
      int L0 = jj * 64;
      int L = L0 + lane;
      int row = L >> 3, ch = (L & 7) * 8;
      size_t go = (size_t)(n0 + row) * 1024 + k0 + ch;
      if (j < 6) GL16(wth + go, &Bh[L0 * 8]);
      else       GL16(wtl + go, &Bl[L0 * 8]);
    }
    __syncthreads();
#pragma unroll
    for (int ks = 0; ks < 2; ++ks){
      s16x8 af_h[2], af_l[2], bf_h[3], bf_l[3];
#pragma unroll
      for (int mf = 0; mf < 2; ++mf){
        int off = (wm + mf * 16 + c) * 64 + ks * 32 + g * 8;
        af_h[mf] = *(const s16x8*)&Ah[off];
        af_l[mf] = *(const s16x8*)&Al[off];
      }
#pragma unroll
      for (int nf = 0; nf < 3; ++nf){
        int off = (nf * 16 + c) * 64 + ks * 32 + g * 8;
        bf_h[nf] = *(const s16x8*)&Bh[off];
        bf_l[nf] = *(const s16x8*)&Bl[off];
      }
#pragma unroll
      for (int mf = 0; mf < 2; ++mf)
#pragma unroll
        for (int nf = 0; nf < 3; ++nf){
          acc[mf][nf] = mfma16(af_h[mf], bf_h[nf], acc[mf][nf]);
          acc[mf][nf] = mfma16(af_h[mf], bf_l[nf], acc[mf][nf]);
          acc[mf][nf] = mfma16(af_l[mf], bf_h[nf], acc[mf][nf]);
        }
    }
  }

#pragma unroll
  for (int mf = 0; mf < 2; ++mf)
#pragma unroll
    for (int nf = 0; nf < 3; ++nf){
      int base_n = n0 + nf * 16;
      int m_base = m0 + wm + mf * 16 + g * 4;
      if (base_n < 256){
        float sc = (base_n < 128) ? QSCALE : 1.0f;
        u16* oh = (base_n < 128) ? qh : kh;
        u16* ol = (base_n < 128) ? ql : kl;
        int d = (base_n & 127) + c;
#pragma unroll
        for (int r = 0; r < 4; ++r){
          float v = acc[mf][nf][r] * sc;
          u16 h = f2bf(v);
          u16 lo = f2bf(v - bf2f(h));
          size_t o = (size_t)(m_base + r) * 128 + d;
          oh[o] = h; ol[o] = lo;
        }
      } else {                       // v, stored transposed [b][d][t]
        int d = base_n - 256 + c;
        int bb = m_base >> 11;
        int tt = m_base & 2047;
        ushort4 ovh, ovl;
#pragma unroll
        for (int r = 0; r < 4; ++r){
          float v = acc[mf][nf][r];
          u16 h = f2bf(v);
          u16 lo = f2bf(v - bf2f(h));
          ((u16*)&ovh)[r] = h;
          ((u16*)&ovl)[r] = lo;
        }
        size_t o = (size_t)bb * (128 * 2048) + (size_t)d * 2048 + tt;
        *(ushort4*)&vth[o] = ovh;
        *(ushort4*)&vtl[o] = ovl;
      }
    }
}

// ---- kernel 3 v4: LDS-staged flash attention partials ----
// r6/r8/r9 showed duration tracks logical K/V traffic (~6.5 TB/s effective
// scattered-read ceiling) and FETCH=40MB (> inputs) = per-XCD L2 thrash.
// Fix: block = 4 waves x one 64-row q-block; K,V (hi+lo, 64 KB) staged ONCE
// per block per k-tile via global_load_lds (coalesced), all waves consume
// from LDS: 540 MB -> 135 MB. Batch pinned to XCD pair via cid&3. XOR
// swizzle both-sides (linear LDS dest + inverse-swizzled global source +
// swizzled ds_read) kills the 16-way row-stride bank conflict. P-bounce
// aliases the K region (barrier-protected). LDS 64 KB -> 2 blocks/CU.
// Chunks: (b, qb, j): q-block qb (64 rows), k-tiles [4j, min(4j+4, qb+1)).
// Per batch: sum_qb ceil((qb+1)/4) = 144 chunks; 576 blocks total.
__global__ __launch_bounds__(256, 2) void attn_partial_kernel(
    const u16* __restrict__ qh, const u16* __restrict__ ql,
    const u16* __restrict__ kh, const u16* __restrict__ kl,
    const u16* __restrict__ vth, const u16* __restrict__ vtl,
    float* __restrict__ partials){
  __shared__ u16 KP[64 * 128 * 2];   // Kh | Kl ; P-bounce aliased after QK^T
  __shared__ u16 VP[128 * 64 * 2];   // Vh | Vl
  int t = threadIdx.x;
  int lane = t & 63, wv = t >> 6;
  int c = lane & 15, g = lane >> 4;
  int cid = blockIdx.x;              // [0, 576)
  int b = cid & 3;                   // batch -> XCD pair {b, b+4}
  int w = cid >> 2;                  // [0, 144) within batch
  int a = 0;
#pragma unroll
  for (int aa = 1; aa < 8; ++aa) if (w >= 2 * aa * (aa + 1)) a = aa;
  int off = w - 2 * a * (a + 1);     // [0, 4*(a+1))
  int qb_l = off / (a + 1);
  int j = off - qb_l * (a + 1);
  int qb = 4 * a + qb_l;             // 64-row q-block, 0..31
  int q0w = qb * 64 + wv * 16;       // this wave's 16 q-rows
  int n = qb + 1;                    // total k-tiles for this q-block
  int kt_lo = 4 * j;
  int kt_hi = min(kt_lo + 4, n);
  int swz = (c & 7) << 3;            // read-side element swizzle
  u16* ph = &KP[wv * 2816];          // P-bounce region (aliases K)
  u16* pl = ph + 1408;

  size_t qrow = ((size_t)b * 2048 + q0w + c) * 128;
  s16x8 qbh[4], qbl[4];
#pragma unroll
  for (int ks = 0; ks < 4; ++ks){
    qbh[ks] = *(const s16x8*)&qh[qrow + ks * 32 + g * 8];
    qbl[ks] = *(const s16x8*)&ql[qrow + ks * 32 + g * 8];
  }

  f32x4 accO[8] = {};
  float m = -INFINITY, lsum = 0.f;

  for (int kt = kt_lo; kt < kt_hi; ++kt){
    __syncthreads();                 // prev P/V reads done before restage
    // ---- cooperative stage: K[64][128] hi/lo + V^T[128][64] hi/lo ----
    // LDS dest linear (wave-uniform base + lane*16); global source carries
    // the inverse swizzle (same XOR as read side -> involution).
#pragma unroll
    for (int i = 0; i < 4; ++i){
      int krow = wv * 16 + i * 4 + (lane >> 4);
      int kcol = ((lane & 15) * 8) ^ ((krow & 7) << 3);
      size_t gk = ((size_t)b * 2048 + kt * 64 + krow) * 128 + kcol;
      GL16(kh + gk, &KP[wv * 2048 + i * 512]);
      GL16(kl + gk, &KP[8192 + wv * 2048 + i * 512]);
      int vrow = wv * 32 + i * 8 + (lane >> 3);
      int vcol = ((lane & 7) * 8) ^ ((vrow & 7) << 3);
      size_t gv = ((size_t)b * 128 + vrow) * 2048 + (size_t)kt * 64 + vcol;
      GL16(vth + gv, &VP[wv * 2048 + i * 512]);
      GL16(vtl + gv, &VP[8192 + wv * 2048 + i * 512]);
    }
    __syncthreads();                 // vmcnt drained by compiler before barrier
    // ---- S^T tile [64k x 16q] from K-LDS (swizzled reads, 2-way max) ----
    f32x4 s4[4] = {};
#pragma unroll
    for (int ks = 0; ks < 4; ++ks){
      int colk = (ks * 32 + g * 8) ^ swz;
      s16x8 ah[4], al[4];
#pragma unroll
      for (int kb = 0; kb < 4; ++kb){
        int ra = (kb * 16 + c) * 128 + colk;
        ah[kb] = *(const s16x8*)&KP[ra];
        al[kb] = *(const s16x8*)&KP[8192 + ra];
      }
#pragma unroll
      for (int kb = 0; kb < 4; ++kb){
        s4[kb] = mfma16(ah[kb], qbh[ks], s4[kb]);
        s4[kb] = mfma16(ah[kb], qbl[ks], s4[kb]);
        s4[kb] = mfma16(al[kb], qbh[ks], s4[kb]);
      }
    }
    if (kt == n - 1){                // causal mask, last tile only
#pragma unroll
      for (int kb = 0; kb < 4; ++kb)
#pragma unroll
        for (int r = 0; r < 4; ++r){
          int kg = kt * 64 + kb * 16 + g * 4 + r;
          if (kg > q0w + c) s4[kb][r] = -3.0e38f;
        }
    }
    // ---- online softmax (row = q0w + (lane&15); 4 lanes per row) ----
    float pmax = s4[0][0];
#pragma unroll
    for (int kb = 0; kb < 4; ++kb)
#pragma unroll
      for (int r = 0; r < 4; ++r) pmax = fmaxf(pmax, s4[kb][r]);
    pmax = fmaxf(pmax, __shfl_xor(pmax, 16));
    pmax = fmaxf(pmax, __shfl_xor(pmax, 32));
    float mnew = fmaxf(m, pmax);
    float corr = exp2f((m - mnew) * LOG2E);
    float psum = 0.f;
    __syncthreads();                 // all waves' K reads done before P write
#pragma unroll
    for (int kb = 0; kb < 4; ++kb){
      ushort4 wh_, wl_;
#pragma unroll
      for (int r = 0; r < 4; ++r){
        float p = exp2f((s4[kb][r] - mnew) * LOG2E);
        psum += p;
        u16 h = f2bf(p);
        ((u16*)&wh_)[r] = h;
        ((u16*)&wl_)[r] = f2bf(p - bf2f(h));
      }
      *(ushort4*)&ph[c * 88 + kb * 16 + g * 4] = wh_;
      *(ushort4*)&pl[c * 88 + kb * 16 + g * 4] = wl_;
    }
    psum += __shfl_xor(psum, 16);
    psum += __shfl_xor(psum, 32);
    lsum = lsum * corr + psum;
    m = mnew;
#pragma unroll
    for (int db = 0; db < 8; ++db)
#pragma unroll
      for (int r = 0; r < 4; ++r) accO[db][r] *= corr;

    // intra-wave bounce: C-layout P -> B-fragment layout (wave-private)
    asm volatile("s_waitcnt lgkmcnt(0)" ::: "memory");
    s16x8 pbh[2], pbl[2];
#pragma unroll
    for (int ks2 = 0; ks2 < 2; ++ks2){
      pbh[ks2] = *(const s16x8*)&ph[c * 88 + ks2 * 32 + g * 8];
      pbl[ks2] = *(const s16x8*)&pl[c * 88 + ks2 * 32 + g * 8];
    }
    // ---- O^T += V^T . P^T from V-LDS (swizzled reads) ----
#pragma unroll
    for (int dh = 0; dh < 4; ++dh){
      s16x8 vh8[2][2], vl8[2][2];
#pragma unroll
      for (int i = 0; i < 2; ++i){
        int db = dh * 2 + i;
#pragma unroll
        for (int ks2 = 0; ks2 < 2; ++ks2){
          int rv = (db * 16 + c) * 64 + ((ks2 * 32 + g * 8) ^ swz);
          vh8[i][ks2] = *(const s16x8*)&VP[rv];
          vl8[i][ks2] = *(const s16x8*)&VP[8192 + rv];
        }
      }
#pragma unroll
      for (int i = 0; i < 2; ++i){
        int db = dh * 2 + i;
#pragma unroll
        for (int ks2 = 0; ks2 < 2; ++ks2){
          accO[db] = mfma16(vh8[i][ks2], pbh[ks2], accO[db]);
          accO[db] = mfma16(vh8[i][ks2], pbl[ks2], accO[db]);
          accO[db] = mfma16(vl8[i][ks2], pbh[ks2], accO[db]);
        }
      }
    }
  }

  // ---- write partial: pslot = cid*4 + wv; { m[16], l[16], O[16][128] } ----
  float* pb = partials + ((size_t)cid * 4 + wv) * 2080;
  if (g == 0){ pb[c] = m; pb[16 + c] = lsum; }
#pragma unroll
  for (int db = 0; db < 8; ++db){
    float4 o4;
    o4.x = accO[db][0]; o4.y = accO[db][1];
    o4.z = accO[db][2]; o4.w = accO[db][3];
    *(float4*)&pb[32 + c * 128 + db * 16 + g * 4] = o4;
  }
}

// ---- kernel 4: merge partials per (b, 16-row q-tile) ----
__global__ __launch_bounds__(256) void attn_merge_kernel(
    const float* __restrict__ partials, float* __restrict__ out){
  int bid = blockIdx.x;              // 512
  int b = bid >> 7, qt16 = bid & 127;
  int qb = qt16 >> 2, wvq = qt16 & 3;
  int a = qb >> 2, qb_l = qb & 3;
  int nc = a + 1;
  int w0 = 2 * a * (a + 1) + qb_l * (a + 1);
  int t = threadIdx.x;
  int q = t >> 4, dgrp = t & 15;
  int d0 = dgrp * 8;

  float M = -INFINITY;
#pragma unroll 1
  for (int jj = 0; jj < nc; ++jj){
    size_t ps = ((size_t)((w0 + jj) * 4 + b) * 4 + wvq) * 2080;
    M = fmaxf(M, partials[ps + q]);
  }
  float L = 0.f;
  float o[8] = {0,0,0,0,0,0,0,0};
#pragma unroll 1
  for (int jj = 0; jj < nc; ++jj){
    const float* pb = partials + ((size_t)((w0 + jj) * 4 + b) * 4 + wvq) * 2080;
    float sc = exp2f((pb[q] - M) * LOG2E);
    L += pb[16 + q] * sc;
    float4 x0 = *(const float4*)&pb[32 + q * 128 + d0];
    float4 x1 = *(const float4*)&pb[32 + q * 128 + d0 + 4];
    o[0] += sc * x0.x; o[1] += sc * x0.y; o[2] += sc * x0.z; o[3] += sc * x0.w;
    o[4] += sc * x1.x; o[5] += sc * x1.y; o[6] += sc * x1.z; o[7] += sc * x1.w;
  }
  float invL = 1.0f / L;
  size_t obase = ((size_t)b * 2048 + qt16 * 16 + q) * 128 + d0;
  float4 r0, r1;
  r0.x = o[0] * invL; r0.y = o[1] * invL; r0.z = o[2] * invL; r0.w = o[3] * invL;
  r1.x = o[4] * invL; r1.y = o[5] * invL; r1.z = o[6] * invL; r1.w = o[7] * invL;
  *(float4*)&out[obase] = r0;
  *(float4*)&out[obase + 4] = r1;
}

extern "C" void kernel_launch(void* const* d_in, const int* in_sizes, int n_in,
                              void* d_out, int out_size, void* d_ws, size_t ws_size,
                              hipStream_t stream){
  (void)in_sizes; (void)n_in; (void)out_size;
  const float* x  = (const float*)d_in[0];
  const float* Wq = (const float*)d_in[1];
  const float* Wk = (const float*)d_in[2];
  const float* Wv = (const float*)d_in[3];
  float* out = (float*)d_out;

  char* ws = (char*)d_ws;
  size_t off = 0;
  auto alloc = [&](size_t bytes) -> void* {
    void* p = ws + off;
    off += (bytes + 255) & ~(size_t)255;
    return p;
  };
  u16* xh  = (u16*)alloc((size_t)8192 * 1024 * 2);
  u16* xl  = (u16*)alloc((size_t)8192 * 1024 * 2);
  u16* wth = (u16*)alloc((size_t)384 * 1024 * 2);
  u16* wtl = (u16*)alloc((size_t)384 * 1024 * 2);
  u16* qh  = (u16*)alloc((size_t)8192 * 128 * 2);
  u16* ql  = (u16*)alloc((size_t)8192 * 128 * 2);
  u16* kh  = (u16*)alloc((size_t)8192 * 128 * 2);
  u16* kl  = (u16*)alloc((size_t)8192 * 128 * 2);
  u16* vth = (u16*)alloc((size_t)8192 * 128 * 2);
  u16* vtl = (u16*)alloc((size_t)8192 * 128 * 2);
  // Partials: 2304 records x 2080 f32 = 19.2 MB, reuse xh/xl (33.5 MB),
  // dead after qkv_gemm. Stream order guarantees gemm completes first.
  float* partials = (float*)xh;

  if (ws_size < off) return;  // never write past the workspace

  prep_kernel<<<4192, 256, 0, stream>>>(x, Wq, Wk, Wv, xh, xl, wth, wtl);
  qkv_gemm_kernel<<<512, 256, 0, stream>>>(xh, xl, wth, wtl,
                                           qh, ql, kh, kl, vth, vtl);
  attn_partial_kernel<<<576, 256, 0, stream>>>(qh, ql, kh, kl, vth, vtl,
                                               partials);
  attn_merge_kernel<<<512, 256, 0, stream>>>(partials, out);
}